// Round 7
// baseline (150.631 us; speedup 1.0000x reference)
//
#include <hip/hip_runtime.h>
#include <math.h>

// Problem constants (fixed by the reference setup)
constexpr int N = 4096;
constexpr int E = 128;
constexpr int H = 8;
constexpr int D = 16;      // E / H
constexpr int SPAN = 50;

// MEASUREMENT-PROBE ROUND: each kernel repeats its compute phase REPS times
// (identical work -> identical output). total' = base + (REPS-1)*kernel_sum,
// and each kernel becomes visible in the rocprof top-5 with its counters.
constexpr int REPS = 4;

// ---------------------------------------------------------------------------
// Shared GEMM building blocks (R4 versions, verbatim).
// ---------------------------------------------------------------------------
__device__ __forceinline__ void gemm_fma4(const float4 x, const float4 w0,
                                          const float4 w1, const float4 w2,
                                          const float4 w3, float4& a)
{
    a.x = fmaf(x.x, w0.x, a.x); a.y = fmaf(x.x, w0.y, a.y);
    a.z = fmaf(x.x, w0.z, a.z); a.w = fmaf(x.x, w0.w, a.w);
    a.x = fmaf(x.y, w1.x, a.x); a.y = fmaf(x.y, w1.y, a.y);
    a.z = fmaf(x.y, w1.z, a.z); a.w = fmaf(x.y, w1.w, a.w);
    a.x = fmaf(x.z, w2.x, a.x); a.y = fmaf(x.z, w2.y, a.y);
    a.z = fmaf(x.z, w2.z, a.z); a.w = fmaf(x.z, w2.w, a.w);
    a.x = fmaf(x.w, w3.x, a.x); a.y = fmaf(x.w, w3.y, a.y);
    a.z = fmaf(x.w, w3.z, a.z); a.w = fmaf(x.w, w3.w, a.w);
}

__device__ __forceinline__ void gemm_half_8x128(
    const float* __restrict__ xs, const float* __restrict__ Wm,
    int h, int c4, int r0, float4 acc[4])
{
    const int kbase = h * 64;
    #pragma unroll 2
    for (int kk = 0; kk < 64; kk += 4) {
        const int k = kbase + kk;
        const float4 w0 = ((const float4*)(Wm + (size_t)(k + 0) * E))[c4];
        const float4 w1 = ((const float4*)(Wm + (size_t)(k + 1) * E))[c4];
        const float4 w2 = ((const float4*)(Wm + (size_t)(k + 2) * E))[c4];
        const float4 w3 = ((const float4*)(Wm + (size_t)(k + 3) * E))[c4];
        #pragma unroll
        for (int i = 0; i < 4; ++i) {
            const float4 x = *(const float4*)&xs[(r0 + i) * E + k];
            gemm_fma4(x, w0, w1, w2, w3, acc[i]);
        }
    }
}

__device__ __forceinline__ void combine_store(
    float* __restrict__ part, const float4 acc[4], int h, int c4, int r0,
    int tid, const float* __restrict__ bias, float* __restrict__ outp, int row0)
{
    #pragma unroll
    for (int i = 0; i < 4; ++i)
        *(float4*)&part[(size_t)(h * 8 + r0 + i) * 132 + c4 * 4] = acc[i];
    __syncthreads();
    #pragma unroll
    for (int rr = 0; rr < 2; ++rr) {
        const int idx = tid + 128 * rr;
        const int row = idx >> 5, q = idx & 31;
        const float4 p0 = *(const float4*)&part[(size_t)row * 132 + q * 4];
        const float4 p1 = *(const float4*)&part[(size_t)(8 + row) * 132 + q * 4];
        const float4 bb = ((const float4*)bias)[q];
        const float4 o  = make_float4(p0.x + p1.x + bb.x, p0.y + p1.y + bb.y,
                                      p0.z + p1.z + bb.z, p0.w + p1.w + bb.w);
        *(float4*)&outp[(size_t)(row0 + row) * E + q * 4] = o;
    }
    __syncthreads();
}

// ---------------------------------------------------------------------------
// Kernel 1: fused projections (R4 version + REPS loop)
// ---------------------------------------------------------------------------
__global__ __launch_bounds__(128) void proj_kernel(
    const float* __restrict__ query, const float* __restrict__ key,
    const float* __restrict__ value, const float* __restrict__ attn_bias,
    const float* __restrict__ Wq, const float* __restrict__ bq,
    const float* __restrict__ Wk, const float* __restrict__ bk,
    const float* __restrict__ Wv, const float* __restrict__ bv,
    const float* __restrict__ Wfe, const float* __restrict__ bfe,
    float* __restrict__ qo, float* __restrict__ ko,
    float* __restrict__ vo, float* __restrict__ bo_)
{
    __shared__ float xs[3][8][E];
    __shared__ float ab[8][8];
    __shared__ float part[2 * 8 * 132];

    const int tid  = threadIdx.x;
    const int c4   = tid & 31;
    const int r0   = ((tid >> 5) & 1) * 4;
    const int h    = tid >> 6;
    const int row0 = blockIdx.x * 8;

    #pragma unroll
    for (int m = 0; m < 3; ++m) {
        const float* s = (m == 0) ? query : (m == 1) ? key : value;
        #pragma unroll
        for (int rr = 0; rr < 2; ++rr) {
            const int idx = tid + 128 * rr;
            const int row = idx >> 5, q = idx & 31;
            *(float4*)&xs[m][row][q * 4] =
                ((const float4*)(s + (size_t)(row0 + row) * E))[q];
        }
    }
    if (tid < 64) ab[tid >> 3][tid & 7] = attn_bias[(size_t)row0 * H + tid];
    __syncthreads();

    for (int rep = 0; rep < REPS; ++rep) {
        asm volatile("" ::: "memory");
        float4 acc[4];

        #pragma unroll
        for (int i = 0; i < 4; ++i) acc[i] = make_float4(0.f, 0.f, 0.f, 0.f);
        gemm_half_8x128(&xs[0][0][0], Wq, h, c4, r0, acc);
        combine_store(part, acc, h, c4, r0, tid, bq, qo, row0);

        #pragma unroll
        for (int i = 0; i < 4; ++i) acc[i] = make_float4(0.f, 0.f, 0.f, 0.f);
        gemm_half_8x128(&xs[1][0][0], Wk, h, c4, r0, acc);
        combine_store(part, acc, h, c4, r0, tid, bk, ko, row0);

        #pragma unroll
        for (int i = 0; i < 4; ++i) acc[i] = make_float4(0.f, 0.f, 0.f, 0.f);
        gemm_half_8x128(&xs[2][0][0], Wv, h, c4, r0, acc);
        combine_store(part, acc, h, c4, r0, tid, bv, vo, row0);

        #pragma unroll
        for (int i = 0; i < 4; ++i) acc[i] = make_float4(0.f, 0.f, 0.f, 0.f);
        {
            const float4 w0 = ((const float4*)(Wfe + (size_t)(h * 4 + 0) * E))[c4];
            const float4 w1 = ((const float4*)(Wfe + (size_t)(h * 4 + 1) * E))[c4];
            const float4 w2 = ((const float4*)(Wfe + (size_t)(h * 4 + 2) * E))[c4];
            const float4 w3 = ((const float4*)(Wfe + (size_t)(h * 4 + 3) * E))[c4];
            #pragma unroll
            for (int i = 0; i < 4; ++i) {
                const float4 x = *(const float4*)&ab[r0 + i][h * 4];
                gemm_fma4(x, w0, w1, w2, w3, acc[i]);
            }
        }
        combine_store(part, acc, h, c4, r0, tid, bfe, bo_, row0);
    }
}

// ---------------------------------------------------------------------------
// Kernel 2: banded attention (R2 version + REPS loop)
// ---------------------------------------------------------------------------
__global__ __launch_bounds__(64, 4) void attn_kernel(
    const float* __restrict__ q, const float* __restrict__ k,
    const float* __restrict__ v, const float* __restrict__ b,
    float* __restrict__ attn)
{
    __shared__ float vt[128][17];
    __shared__ float ew[104];

    const int lane = threadIdx.x;
    const int bid  = blockIdx.x;
    const int h    = bid & 7;
    const int i0   = (bid >> 3) * 8;
    const int base = i0 - SPAN;

    #pragma unroll
    for (int rep = 0; rep < 2; ++rep) {
        const int r = rep * 64 + lane;
        int j = base + r;
        j = j < 0 ? 0 : (j > N - 1 ? N - 1 : j);
        const float4* vp = (const float4*)(v + (size_t)j * E + h * D);
        #pragma unroll
        for (int qt = 0; qt < 4; ++qt) {
            const float4 t = vp[qt];
            vt[r][qt * 4 + 0] = t.x; vt[r][qt * 4 + 1] = t.y;
            vt[r][qt * 4 + 2] = t.z; vt[r][qt * 4 + 3] = t.w;
        }
    }

    const int p0 = base + lane;
    const int p1 = p0 + 64;
    const bool in0 = (p0 >= 0) && (p0 < N);
    const bool in1 = (p1 >= 0) && (p1 < N);
    const int c0 = p0 < 0 ? 0 : (p0 > N - 1 ? N - 1 : p0);
    const int c1 = p1 < 0 ? 0 : (p1 > N - 1 ? N - 1 : p1);

    float k0[16], k1[16], g0[16], g1[16];
    {
        const float4* kp0 = (const float4*)(k + (size_t)c0 * E + h * D);
        const float4* kp1 = (const float4*)(k + (size_t)c1 * E + h * D);
        const float4* gp0 = (const float4*)(b + (size_t)c0 * E + h * D);
        const float4* gp1 = (const float4*)(b + (size_t)c1 * E + h * D);
        #pragma unroll
        for (int x = 0; x < 4; ++x) {
            float4 t;
            t = kp0[x]; k0[4*x]=t.x; k0[4*x+1]=t.y; k0[4*x+2]=t.z; k0[4*x+3]=t.w;
            t = kp1[x]; k1[4*x]=t.x; k1[4*x+1]=t.y; k1[4*x+2]=t.z; k1[4*x+3]=t.w;
            t = gp0[x]; g0[4*x]=t.x; g0[4*x+1]=t.y; g0[4*x+2]=t.z; g0[4*x+3]=t.w;
            t = gp1[x]; g1[4*x]=t.x; g1[4*x+1]=t.y; g1[4*x+2]=t.z; g1[4*x+3]=t.w;
        }
    }
    __syncthreads();

    const float scale = 1.0f / 64.0f;
    const int d = lane & 15;
    const int g = lane >> 4;

    for (int rep = 0; rep < REPS; ++rep) {
        asm volatile("" ::: "memory");
        for (int r = 0; r < 8; ++r) {
            const float* qp = q + (size_t)(i0 + r) * E + h * D;
            const float* bp = b + (size_t)(i0 + r) * E + h * D;

            float sq0 = 0.f, sb0 = 0.f, sq1 = 0.f, sb1 = 0.f;
            #pragma unroll
            for (int x = 0; x < 16; ++x) {
                const float qv = qp[x];
                const float bv = bp[x];
                sq0 = fmaf(qv, k0[x], sq0);
                sq1 = fmaf(qv, k1[x], sq1);
                sb0 = fmaf(bv, g0[x], sb0);
                sb1 = fmaf(bv, g1[x], sb1);
            }
            const bool valid0 = in0 && (lane >= r);
            const bool valid1 = in1 && (lane <= r + 36);
            const float s0 = valid0 ? sq0 * scale + sb0 : -INFINITY;
            const float s1 = valid1 ? sq1 * scale + sb1 : -INFINITY;

            float m = fmaxf(s0, s1);
            #pragma unroll
            for (int off = 32; off; off >>= 1) m = fmaxf(m, __shfl_xor(m, off));

            const float e0 = __expf(s0 - m);
            const float e1 = __expf(s1 - m);

            float sum = e0 + e1;
            #pragma unroll
            for (int off = 32; off; off >>= 1) sum += __shfl_xor(sum, off);
            const float inv = 1.0f / sum;

            if (lane >= r)      ew[lane - r]      = e0;
            if (lane <= r + 36) ew[64 + lane - r] = e1;
            __syncthreads();

            float acc = 0.f;
            #pragma unroll
            for (int it = 0; it < 25; ++it) {
                const int w = g + 4 * it;
                acc = fmaf(ew[w], vt[w + r][d], acc);
            }
            if (g == 0) acc = fmaf(ew[100], vt[100 + r][d], acc);

            acc += __shfl_xor(acc, 16);
            acc += __shfl_xor(acc, 32);

            if (lane < D) attn[(size_t)(i0 + r) * E + h * D + lane] = acc * inv;
            __syncthreads();
        }
    }
}

// ---------------------------------------------------------------------------
// Kernel 3: output projection (R4 version + REPS loop)
// ---------------------------------------------------------------------------
__global__ __launch_bounds__(128) void out_kernel(
    const float* __restrict__ attn, const float* __restrict__ Wo,
    const float* __restrict__ bo, float* __restrict__ out)
{
    __shared__ float xs[8][E];
    __shared__ float part[2 * 8 * 132];

    const int tid  = threadIdx.x;
    const int c4   = tid & 31;
    const int r0   = ((tid >> 5) & 1) * 4;
    const int h    = tid >> 6;
    const int row0 = blockIdx.x * 8;

    #pragma unroll
    for (int rr = 0; rr < 2; ++rr) {
        const int idx = tid + 128 * rr;
        const int row = idx >> 5, q = idx & 31;
        *(float4*)&xs[row][q * 4] =
            ((const float4*)(attn + (size_t)(row0 + row) * E))[q];
    }
    __syncthreads();

    for (int rep = 0; rep < REPS; ++rep) {
        asm volatile("" ::: "memory");
        float4 acc[4];
        #pragma unroll
        for (int i = 0; i < 4; ++i) acc[i] = make_float4(0.f, 0.f, 0.f, 0.f);
        gemm_half_8x128(&xs[0][0], Wo, h, c4, r0, acc);
        combine_store(part, acc, h, c4, r0, tid, bo, out, row0);
    }
}

// ---------------------------------------------------------------------------
extern "C" void kernel_launch(void* const* d_in, const int* in_sizes, int n_in,
                              void* d_out, int out_size, void* d_ws, size_t ws_size,
                              hipStream_t stream) {
    const float* query     = (const float*)d_in[0];
    const float* key       = (const float*)d_in[1];
    const float* value     = (const float*)d_in[2];
    const float* attn_bias = (const float*)d_in[3];
    const float* Wq  = (const float*)d_in[4];
    const float* bq  = (const float*)d_in[5];
    const float* Wk  = (const float*)d_in[6];
    const float* bk  = (const float*)d_in[7];
    const float* Wv  = (const float*)d_in[8];
    const float* bv  = (const float*)d_in[9];
    const float* Wo  = (const float*)d_in[10];
    const float* bo  = (const float*)d_in[11];
    const float* Wfe = (const float*)d_in[12];
    const float* bfe = (const float*)d_in[13];

    float* ws = (float*)d_ws;
    const int NE = N * E;
    float* qw    = ws;
    float* kw    = ws + 1 * NE;
    float* vw    = ws + 2 * NE;
    float* bw    = ws + 3 * NE;
    float* attnw = ws + 4 * NE;

    proj_kernel<<<N / 8, 128, 0, stream>>>(query, key, value, attn_bias,
                                           Wq, bq, Wk, bk, Wv, bv, Wfe, bfe,
                                           qw, kw, vw, bw);
    attn_kernel<<<(N / 8) * H, 64, 0, stream>>>(qw, kw, vw, bw, attnw);
    out_kernel<<<N / 8, 128, 0, stream>>>(attnw, Wo, bo, (float*)d_out);
}

// Round 8
// 66.967 us; speedup vs baseline: 2.2493x; 2.2493x over previous
//
#include <hip/hip_runtime.h>
#include <math.h>

// Problem constants (fixed by the reference setup)
constexpr int N = 4096;
constexpr int E = 128;
constexpr int H = 8;
constexpr int D = 16;      // E / H
constexpr int SPAN = 50;

// 16 FMAs: acc[c] += sum_j x[j] * wj[c]
__device__ __forceinline__ void fma4x4(const float4 x, const float4 w0,
                                       const float4 w1, const float4 w2,
                                       const float4 w3, float4& a)
{
    a.x = fmaf(x.x, w0.x, a.x); a.y = fmaf(x.x, w0.y, a.y);
    a.z = fmaf(x.x, w0.z, a.z); a.w = fmaf(x.x, w0.w, a.w);
    a.x = fmaf(x.y, w1.x, a.x); a.y = fmaf(x.y, w1.y, a.y);
    a.z = fmaf(x.y, w1.z, a.z); a.w = fmaf(x.y, w1.w, a.w);
    a.x = fmaf(x.z, w2.x, a.x); a.y = fmaf(x.z, w2.y, a.y);
    a.z = fmaf(x.z, w2.z, a.z); a.w = fmaf(x.z, w2.w, a.w);
    a.x = fmaf(x.w, w3.x, a.x); a.y = fmaf(x.w, w3.y, a.y);
    a.z = fmaf(x.w, w3.z, a.z); a.w = fmaf(x.w, w3.w, a.w);
}

// ---------------------------------------------------------------------------
// Kernel 1: projections, one matrix per block-third of the grid.
// Grid = 1536 blocks x 256 threads: mat = bid>>9 (0=q,1=k,2=v),
// 8-row tile, thread = (c4 = tid&31 -> 4 cols, row = tid>>5).
// 6144 waves = 24 waves/CU: latency hidden by TLP, no barriers after staging.
// mat==0 blocks also compute the (K=8) feature projection for their rows.
// ---------------------------------------------------------------------------
__global__ __launch_bounds__(256) void proj_kernel(
    const float* __restrict__ query, const float* __restrict__ key,
    const float* __restrict__ value, const float* __restrict__ attn_bias,
    const float* __restrict__ Wq, const float* __restrict__ bq,
    const float* __restrict__ Wk, const float* __restrict__ bk,
    const float* __restrict__ Wv, const float* __restrict__ bv,
    const float* __restrict__ Wfe, const float* __restrict__ bfe,
    float* __restrict__ qo, float* __restrict__ ko,
    float* __restrict__ vo, float* __restrict__ bo_)
{
    __shared__ __align__(16) float xs[8 * 128];
    __shared__ float ab[64];

    const int tid  = threadIdx.x;
    const int c4   = tid & 31;
    const int row  = tid >> 5;                 // 0..7
    const int bid  = blockIdx.x;
    const int mat  = bid >> 9;                 // 0..2
    const int row0 = (bid & 511) * 8;

    const float* src = mat == 0 ? query : (mat == 1 ? key : value);
    const float* Wm  = mat == 0 ? Wq : (mat == 1 ? Wk : Wv);
    const float* bm  = mat == 0 ? bq : (mat == 1 ? bk : bv);
    float*       dst = mat == 0 ? qo : (mat == 1 ? ko : vo);

    // stage the 8x128 X tile (one float4 per thread, coalesced)
    *(float4*)&xs[row * 128 + c4 * 4] =
        ((const float4*)(src + (size_t)(row0 + row) * E))[c4];
    if (mat == 0 && tid < 64) ab[tid] = attn_bias[(size_t)row0 * H + tid];
    __syncthreads();

    float4 acc = ((const float4*)bm)[c4];
    #pragma unroll 2
    for (int kk = 0; kk < E; kk += 4) {
        const float4 w0 = ((const float4*)(Wm + (size_t)(kk + 0) * E))[c4];
        const float4 w1 = ((const float4*)(Wm + (size_t)(kk + 1) * E))[c4];
        const float4 w2 = ((const float4*)(Wm + (size_t)(kk + 2) * E))[c4];
        const float4 w3 = ((const float4*)(Wm + (size_t)(kk + 3) * E))[c4];
        const float4 x  = *(const float4*)&xs[row * 128 + kk];
        fma4x4(x, w0, w1, w2, w3, acc);
    }
    *(float4*)(dst + (size_t)(row0 + row) * E + c4 * 4) = acc;

    if (mat == 0) {
        // feature projection: b = attn_bias @ Wfe + bfe  (K = 8)
        float4 accb = ((const float4*)bfe)[c4];
        const float4 x0 = *(const float4*)&ab[row * 8];
        const float4 x1 = *(const float4*)&ab[row * 8 + 4];
        const float4 w0 = ((const float4*)(Wfe + 0 * E))[c4];
        const float4 w1 = ((const float4*)(Wfe + 1 * E))[c4];
        const float4 w2 = ((const float4*)(Wfe + 2 * E))[c4];
        const float4 w3 = ((const float4*)(Wfe + 3 * E))[c4];
        fma4x4(x0, w0, w1, w2, w3, accb);
        const float4 w4 = ((const float4*)(Wfe + 4 * E))[c4];
        const float4 w5 = ((const float4*)(Wfe + 5 * E))[c4];
        const float4 w6 = ((const float4*)(Wfe + 6 * E))[c4];
        const float4 w7 = ((const float4*)(Wfe + 7 * E))[c4];
        fma4x4(x1, w4, w5, w6, w7, accb);
        *(float4*)(bo_ + (size_t)(row0 + row) * E + c4 * 4) = accb;
    }
}

// ---------------------------------------------------------------------------
// Kernel 2: banded attention (R2 version, verbatim — known good, ~8 us).
// One 64-thread block per (8-row tile, head).
// ---------------------------------------------------------------------------
__global__ __launch_bounds__(64, 4) void attn_kernel(
    const float* __restrict__ q, const float* __restrict__ k,
    const float* __restrict__ v, const float* __restrict__ b,
    float* __restrict__ attn)
{
    __shared__ float vt[128][17];
    __shared__ float ew[104];

    const int lane = threadIdx.x;
    const int bid  = blockIdx.x;
    const int h    = bid & 7;
    const int i0   = (bid >> 3) * 8;
    const int base = i0 - SPAN;

    #pragma unroll
    for (int rep = 0; rep < 2; ++rep) {
        const int r = rep * 64 + lane;
        int j = base + r;
        j = j < 0 ? 0 : (j > N - 1 ? N - 1 : j);
        const float4* vp = (const float4*)(v + (size_t)j * E + h * D);
        #pragma unroll
        for (int qt = 0; qt < 4; ++qt) {
            const float4 t = vp[qt];
            vt[r][qt * 4 + 0] = t.x; vt[r][qt * 4 + 1] = t.y;
            vt[r][qt * 4 + 2] = t.z; vt[r][qt * 4 + 3] = t.w;
        }
    }

    const int p0 = base + lane;
    const int p1 = p0 + 64;
    const bool in0 = (p0 >= 0) && (p0 < N);
    const bool in1 = (p1 >= 0) && (p1 < N);
    const int c0 = p0 < 0 ? 0 : (p0 > N - 1 ? N - 1 : p0);
    const int c1 = p1 < 0 ? 0 : (p1 > N - 1 ? N - 1 : p1);

    float k0[16], k1[16], g0[16], g1[16];
    {
        const float4* kp0 = (const float4*)(k + (size_t)c0 * E + h * D);
        const float4* kp1 = (const float4*)(k + (size_t)c1 * E + h * D);
        const float4* gp0 = (const float4*)(b + (size_t)c0 * E + h * D);
        const float4* gp1 = (const float4*)(b + (size_t)c1 * E + h * D);
        #pragma unroll
        for (int x = 0; x < 4; ++x) {
            float4 t;
            t = kp0[x]; k0[4*x]=t.x; k0[4*x+1]=t.y; k0[4*x+2]=t.z; k0[4*x+3]=t.w;
            t = kp1[x]; k1[4*x]=t.x; k1[4*x+1]=t.y; k1[4*x+2]=t.z; k1[4*x+3]=t.w;
            t = gp0[x]; g0[4*x]=t.x; g0[4*x+1]=t.y; g0[4*x+2]=t.z; g0[4*x+3]=t.w;
            t = gp1[x]; g1[4*x]=t.x; g1[4*x+1]=t.y; g1[4*x+2]=t.z; g1[4*x+3]=t.w;
        }
    }
    __syncthreads();

    const float scale = 1.0f / 64.0f;    // 1/sqrt(4096)
    const int d = lane & 15;
    const int g = lane >> 4;

    for (int r = 0; r < 8; ++r) {
        const float* qp = q + (size_t)(i0 + r) * E + h * D;
        const float* bp = b + (size_t)(i0 + r) * E + h * D;

        float sq0 = 0.f, sb0 = 0.f, sq1 = 0.f, sb1 = 0.f;
        #pragma unroll
        for (int x = 0; x < 16; ++x) {
            const float qv = qp[x];
            const float bv = bp[x];
            sq0 = fmaf(qv, k0[x], sq0);
            sq1 = fmaf(qv, k1[x], sq1);
            sb0 = fmaf(bv, g0[x], sb0);
            sb1 = fmaf(bv, g1[x], sb1);
        }
        const bool valid0 = in0 && (lane >= r);
        const bool valid1 = in1 && (lane <= r + 36);
        const float s0 = valid0 ? sq0 * scale + sb0 : -INFINITY;
        const float s1 = valid1 ? sq1 * scale + sb1 : -INFINITY;

        float m = fmaxf(s0, s1);
        #pragma unroll
        for (int off = 32; off; off >>= 1) m = fmaxf(m, __shfl_xor(m, off));

        const float e0 = __expf(s0 - m);
        const float e1 = __expf(s1 - m);

        float sum = e0 + e1;
        #pragma unroll
        for (int off = 32; off; off >>= 1) sum += __shfl_xor(sum, off);
        const float inv = 1.0f / sum;

        if (lane >= r)      ew[lane - r]      = e0;
        if (lane <= r + 36) ew[64 + lane - r] = e1;
        __syncthreads();

        float acc = 0.f;
        #pragma unroll
        for (int it = 0; it < 25; ++it) {
            const int w = g + 4 * it;
            acc = fmaf(ew[w], vt[w + r][d], acc);
        }
        if (g == 0) acc = fmaf(ew[100], vt[100 + r][d], acc);

        acc += __shfl_xor(acc, 16);
        acc += __shfl_xor(acc, 32);

        if (lane < D) attn[(size_t)(i0 + r) * E + h * D + lane] = acc * inv;
        __syncthreads();
    }
}

// ---------------------------------------------------------------------------
// Kernel 3: output projection, same high-occupancy structure as proj.
// 512 blocks x 256 threads, 8-row tile, thread = (c4, row).
// ---------------------------------------------------------------------------
__global__ __launch_bounds__(256) void out_kernel(
    const float* __restrict__ attn, const float* __restrict__ Wo,
    const float* __restrict__ bo, float* __restrict__ out)
{
    __shared__ __align__(16) float xs[8 * 128];

    const int tid  = threadIdx.x;
    const int c4   = tid & 31;
    const int row  = tid >> 5;
    const int row0 = blockIdx.x * 8;

    *(float4*)&xs[row * 128 + c4 * 4] =
        ((const float4*)(attn + (size_t)(row0 + row) * E))[c4];
    __syncthreads();

    float4 acc = ((const float4*)bo)[c4];
    #pragma unroll 2
    for (int kk = 0; kk < E; kk += 4) {
        const float4 w0 = ((const float4*)(Wo + (size_t)(kk + 0) * E))[c4];
        const float4 w1 = ((const float4*)(Wo + (size_t)(kk + 1) * E))[c4];
        const float4 w2 = ((const float4*)(Wo + (size_t)(kk + 2) * E))[c4];
        const float4 w3 = ((const float4*)(Wo + (size_t)(kk + 3) * E))[c4];
        const float4 x  = *(const float4*)&xs[row * 128 + kk];
        fma4x4(x, w0, w1, w2, w3, acc);
    }
    *(float4*)(out + (size_t)(row0 + row) * E + c4 * 4) = acc;
}

// ---------------------------------------------------------------------------
extern "C" void kernel_launch(void* const* d_in, const int* in_sizes, int n_in,
                              void* d_out, int out_size, void* d_ws, size_t ws_size,
                              hipStream_t stream) {
    const float* query     = (const float*)d_in[0];
    const float* key       = (const float*)d_in[1];
    const float* value     = (const float*)d_in[2];
    const float* attn_bias = (const float*)d_in[3];
    const float* Wq  = (const float*)d_in[4];
    const float* bq  = (const float*)d_in[5];
    const float* Wk  = (const float*)d_in[6];
    const float* bk  = (const float*)d_in[7];
    const float* Wv  = (const float*)d_in[8];
    const float* bv  = (const float*)d_in[9];
    const float* Wo  = (const float*)d_in[10];
    const float* bo  = (const float*)d_in[11];
    const float* Wfe = (const float*)d_in[12];
    const float* bfe = (const float*)d_in[13];

    float* ws = (float*)d_ws;
    const int NE = N * E;
    float* qw    = ws;
    float* kw    = ws + 1 * NE;
    float* vw    = ws + 2 * NE;
    float* bw    = ws + 3 * NE;
    float* attnw = ws + 4 * NE;

    proj_kernel<<<3 * (N / 8), 256, 0, stream>>>(query, key, value, attn_bias,
                                                 Wq, bq, Wk, bk, Wv, bv,
                                                 Wfe, bfe, qw, kw, vw, bw);
    attn_kernel<<<(N / 8) * H, 64, 0, stream>>>(qw, kw, vw, bw, attnw);
    out_kernel<<<N / 8, 256, 0, stream>>>(attnw, Wo, bo, (float*)d_out);
}

// Round 9
// 53.542 us; speedup vs baseline: 2.8133x; 1.2507x over previous
//
#include <hip/hip_runtime.h>
#include <math.h>

// Problem constants (fixed by the reference setup)
constexpr int N = 4096;
constexpr int E = 128;
constexpr int H = 8;
constexpr int D = 16;      // E / H
constexpr int SPAN = 50;

// 16 FMAs: acc[c] += x[j] * wj[c]
__device__ __forceinline__ void fma4x4(const float4 x, const float4 w0,
                                       const float4 w1, const float4 w2,
                                       const float4 w3, float4& a)
{
    a.x = fmaf(x.x, w0.x, a.x); a.y = fmaf(x.x, w0.y, a.y);
    a.z = fmaf(x.x, w0.z, a.z); a.w = fmaf(x.x, w0.w, a.w);
    a.x = fmaf(x.y, w1.x, a.x); a.y = fmaf(x.y, w1.y, a.y);
    a.z = fmaf(x.y, w1.z, a.z); a.w = fmaf(x.y, w1.w, a.w);
    a.x = fmaf(x.z, w2.x, a.x); a.y = fmaf(x.z, w2.y, a.y);
    a.z = fmaf(x.z, w2.z, a.z); a.w = fmaf(x.z, w2.w, a.w);
    a.x = fmaf(x.w, w3.x, a.x); a.y = fmaf(x.w, w3.y, a.y);
    a.z = fmaf(x.w, w3.z, a.z); a.w = fmaf(x.w, w3.w, a.w);
}

// ---------------------------------------------------------------------------
// Kernel 1: projections. Balanced W-traffic / occupancy point:
//   thread = 2 rows x 4 cols (A=8 acc elems), wave covers 64 cols x 8 rows,
//   block (256 thr = 4 waves) = 16 rows x 128 cols; grid = 3 mats x 256.
//   -> 3072 waves (3 waves/SIMD TLP) and W traffic = 12.6MB x C/A = 100MB
//      (L2-resident: all W = 192KB), ~3us at L2 BW.
// Per 4-k group: 4 coalesced W float4 loads + 2 broadcast ds_read_b128 + 32 FMA.
// mat==0 blocks also do the (K=8) feature projection.
// ---------------------------------------------------------------------------
__global__ __launch_bounds__(256) void proj_kernel(
    const float* __restrict__ query, const float* __restrict__ key,
    const float* __restrict__ value, const float* __restrict__ attn_bias,
    const float* __restrict__ Wq, const float* __restrict__ bq,
    const float* __restrict__ Wk, const float* __restrict__ bk,
    const float* __restrict__ Wv, const float* __restrict__ bv,
    const float* __restrict__ Wfe, const float* __restrict__ bfe,
    float* __restrict__ qo, float* __restrict__ ko,
    float* __restrict__ vo, float* __restrict__ bo_)
{
    __shared__ __align__(16) float xs[16 * 128];   // 8KB X tile
    __shared__ float ab[16 * 8];

    const int tid  = threadIdx.x;
    const int lane = tid & 63;
    const int wv   = tid >> 6;
    const int ch   = wv & 1;          // column half (0..1)
    const int rh   = wv >> 1;         // row half (0..1)
    const int c4   = lane & 15;       // col quad within half
    const int rq   = lane >> 4;       // 0..3
    const int bid  = blockIdx.x;
    const int mat  = bid >> 8;        // 0=q, 1=k, 2=v
    const int row0 = (bid & 255) * 16;

    const float* src = mat == 0 ? query : (mat == 1 ? key : value);
    const float* Wm  = mat == 0 ? Wq : (mat == 1 ? Wk : Wv);
    const float* bm  = mat == 0 ? bq : (mat == 1 ? bk : bv);
    float*       dst = mat == 0 ? qo : (mat == 1 ? ko : vo);

    // ---- stage the 16x128 X tile (2 coalesced float4 per thread) ----
    #pragma unroll
    for (int p = 0; p < 2; ++p) {
        const int idx = tid + 256 * p;
        const int row = idx >> 5, q = idx & 31;
        *(float4*)&xs[row * 128 + q * 4] =
            ((const float4*)(src + (size_t)(row0 + row) * E))[q];
    }
    if (mat == 0 && tid < 128) ab[tid] = attn_bias[(size_t)row0 * H + tid];
    __syncthreads();

    const int cq = ch * 16 + c4;          // global col quad (0..31)
    const int r0 = rh * 8 + rq;           // first row
    const int r1 = r0 + 4;                // second row

    float4 a0 = ((const float4*)bm)[cq];
    float4 a1 = a0;

    #pragma unroll 2
    for (int kk = 0; kk < E; kk += 4) {
        const float4 w0 = ((const float4*)(Wm + (size_t)(kk + 0) * E))[cq];
        const float4 w1 = ((const float4*)(Wm + (size_t)(kk + 1) * E))[cq];
        const float4 w2 = ((const float4*)(Wm + (size_t)(kk + 2) * E))[cq];
        const float4 w3 = ((const float4*)(Wm + (size_t)(kk + 3) * E))[cq];
        const float4 x0 = *(const float4*)&xs[r0 * 128 + kk];
        const float4 x1 = *(const float4*)&xs[r1 * 128 + kk];
        fma4x4(x0, w0, w1, w2, w3, a0);
        fma4x4(x1, w0, w1, w2, w3, a1);
    }
    *(float4*)(dst + (size_t)(row0 + r0) * E + cq * 4) = a0;
    *(float4*)(dst + (size_t)(row0 + r1) * E + cq * 4) = a1;

    if (mat == 0) {
        // feature projection: b = attn_bias @ Wfe + bfe  (K = 8)
        float4 b0 = ((const float4*)bfe)[cq];
        float4 b1 = b0;
        const float4 w0 = ((const float4*)(Wfe + 0 * E))[cq];
        const float4 w1 = ((const float4*)(Wfe + 1 * E))[cq];
        const float4 w2 = ((const float4*)(Wfe + 2 * E))[cq];
        const float4 w3 = ((const float4*)(Wfe + 3 * E))[cq];
        const float4 w4 = ((const float4*)(Wfe + 4 * E))[cq];
        const float4 w5 = ((const float4*)(Wfe + 5 * E))[cq];
        const float4 w6 = ((const float4*)(Wfe + 6 * E))[cq];
        const float4 w7 = ((const float4*)(Wfe + 7 * E))[cq];
        const float4 xa0 = *(const float4*)&ab[r0 * 8];
        const float4 xa1 = *(const float4*)&ab[r0 * 8 + 4];
        const float4 xb0 = *(const float4*)&ab[r1 * 8];
        const float4 xb1 = *(const float4*)&ab[r1 * 8 + 4];
        fma4x4(xa0, w0, w1, w2, w3, b0);
        fma4x4(xa1, w4, w5, w6, w7, b0);
        fma4x4(xb0, w0, w1, w2, w3, b1);
        fma4x4(xb1, w4, w5, w6, w7, b1);
        *(float4*)(bo_ + (size_t)(row0 + r0) * E + cq * 4) = b0;
        *(float4*)(bo_ + (size_t)(row0 + r1) * E + cq * 4) = b1;
    }
}

// ---------------------------------------------------------------------------
// Kernel 2: banded attention (R2 version, verbatim — measured-good).
// ---------------------------------------------------------------------------
__global__ __launch_bounds__(64, 4) void attn_kernel(
    const float* __restrict__ q, const float* __restrict__ k,
    const float* __restrict__ v, const float* __restrict__ b,
    float* __restrict__ attn)
{
    __shared__ float vt[128][17];
    __shared__ float ew[104];

    const int lane = threadIdx.x;
    const int bid  = blockIdx.x;
    const int h    = bid & 7;
    const int i0   = (bid >> 3) * 8;
    const int base = i0 - SPAN;

    #pragma unroll
    for (int rep = 0; rep < 2; ++rep) {
        const int r = rep * 64 + lane;
        int j = base + r;
        j = j < 0 ? 0 : (j > N - 1 ? N - 1 : j);
        const float4* vp = (const float4*)(v + (size_t)j * E + h * D);
        #pragma unroll
        for (int qt = 0; qt < 4; ++qt) {
            const float4 t = vp[qt];
            vt[r][qt * 4 + 0] = t.x; vt[r][qt * 4 + 1] = t.y;
            vt[r][qt * 4 + 2] = t.z; vt[r][qt * 4 + 3] = t.w;
        }
    }

    const int p0 = base + lane;
    const int p1 = p0 + 64;
    const bool in0 = (p0 >= 0) && (p0 < N);
    const bool in1 = (p1 >= 0) && (p1 < N);
    const int c0 = p0 < 0 ? 0 : (p0 > N - 1 ? N - 1 : p0);
    const int c1 = p1 < 0 ? 0 : (p1 > N - 1 ? N - 1 : p1);

    float k0[16], k1[16], g0[16], g1[16];
    {
        const float4* kp0 = (const float4*)(k + (size_t)c0 * E + h * D);
        const float4* kp1 = (const float4*)(k + (size_t)c1 * E + h * D);
        const float4* gp0 = (const float4*)(b + (size_t)c0 * E + h * D);
        const float4* gp1 = (const float4*)(b + (size_t)c1 * E + h * D);
        #pragma unroll
        for (int x = 0; x < 4; ++x) {
            float4 t;
            t = kp0[x]; k0[4*x]=t.x; k0[4*x+1]=t.y; k0[4*x+2]=t.z; k0[4*x+3]=t.w;
            t = kp1[x]; k1[4*x]=t.x; k1[4*x+1]=t.y; k1[4*x+2]=t.z; k1[4*x+3]=t.w;
            t = gp0[x]; g0[4*x]=t.x; g0[4*x+1]=t.y; g0[4*x+2]=t.z; g0[4*x+3]=t.w;
            t = gp1[x]; g1[4*x]=t.x; g1[4*x+1]=t.y; g1[4*x+2]=t.z; g1[4*x+3]=t.w;
        }
    }
    __syncthreads();

    const float scale = 1.0f / 64.0f;    // 1/sqrt(4096)
    const int d = lane & 15;
    const int g = lane >> 4;

    for (int r = 0; r < 8; ++r) {
        const float* qp = q + (size_t)(i0 + r) * E + h * D;
        const float* bp = b + (size_t)(i0 + r) * E + h * D;

        float sq0 = 0.f, sb0 = 0.f, sq1 = 0.f, sb1 = 0.f;
        #pragma unroll
        for (int x = 0; x < 16; ++x) {
            const float qv = qp[x];
            const float bv = bp[x];
            sq0 = fmaf(qv, k0[x], sq0);
            sq1 = fmaf(qv, k1[x], sq1);
            sb0 = fmaf(bv, g0[x], sb0);
            sb1 = fmaf(bv, g1[x], sb1);
        }
        const bool valid0 = in0 && (lane >= r);
        const bool valid1 = in1 && (lane <= r + 36);
        const float s0 = valid0 ? sq0 * scale + sb0 : -INFINITY;
        const float s1 = valid1 ? sq1 * scale + sb1 : -INFINITY;

        float m = fmaxf(s0, s1);
        #pragma unroll
        for (int off = 32; off; off >>= 1) m = fmaxf(m, __shfl_xor(m, off));

        const float e0 = __expf(s0 - m);
        const float e1 = __expf(s1 - m);

        float sum = e0 + e1;
        #pragma unroll
        for (int off = 32; off; off >>= 1) sum += __shfl_xor(sum, off);
        const float inv = 1.0f / sum;

        if (lane >= r)      ew[lane - r]      = e0;
        if (lane <= r + 36) ew[64 + lane - r] = e1;
        __syncthreads();

        float acc = 0.f;
        #pragma unroll
        for (int it = 0; it < 25; ++it) {
            const int w = g + 4 * it;
            acc = fmaf(ew[w], vt[w + r][d], acc);
        }
        if (g == 0) acc = fmaf(ew[100], vt[100 + r][d], acc);

        acc += __shfl_xor(acc, 16);
        acc += __shfl_xor(acc, 32);

        if (lane < D) attn[(size_t)(i0 + r) * E + h * D + lane] = acc * inv;
        __syncthreads();
    }
}

// ---------------------------------------------------------------------------
// Kernel 3: output projection (R4/R5 split-K version, verbatim).
// ---------------------------------------------------------------------------
__device__ __forceinline__ void gemm_half_8x128(
    const float* __restrict__ xs, const float* __restrict__ Wm,
    int h, int c4, int r0, float4 acc[4])
{
    const int kbase = h * 64;
    #pragma unroll 2
    for (int kk = 0; kk < 64; kk += 4) {
        const int k = kbase + kk;
        const float4 w0 = ((const float4*)(Wm + (size_t)(k + 0) * E))[c4];
        const float4 w1 = ((const float4*)(Wm + (size_t)(k + 1) * E))[c4];
        const float4 w2 = ((const float4*)(Wm + (size_t)(k + 2) * E))[c4];
        const float4 w3 = ((const float4*)(Wm + (size_t)(k + 3) * E))[c4];
        #pragma unroll
        for (int i = 0; i < 4; ++i) {
            const float4 x = *(const float4*)&xs[(r0 + i) * E + k];
            fma4x4(x, w0, w1, w2, w3, acc[i]);
        }
    }
}

__global__ __launch_bounds__(128) void out_kernel(
    const float* __restrict__ attn, const float* __restrict__ Wo,
    const float* __restrict__ bo, float* __restrict__ out)
{
    __shared__ float xs[8][E];
    __shared__ float part[2 * 8 * 132];

    const int tid  = threadIdx.x;
    const int c4   = tid & 31;
    const int r0   = ((tid >> 5) & 1) * 4;
    const int h    = tid >> 6;
    const int row0 = blockIdx.x * 8;

    #pragma unroll
    for (int rr = 0; rr < 2; ++rr) {
        const int idx = tid + 128 * rr;
        const int row = idx >> 5, q = idx & 31;
        *(float4*)&xs[row][q * 4] =
            ((const float4*)(attn + (size_t)(row0 + row) * E))[q];
    }
    __syncthreads();

    float4 acc[4];
    #pragma unroll
    for (int i = 0; i < 4; ++i) acc[i] = make_float4(0.f, 0.f, 0.f, 0.f);
    gemm_half_8x128(&xs[0][0], Wo, h, c4, r0, acc);

    #pragma unroll
    for (int i = 0; i < 4; ++i)
        *(float4*)&part[(size_t)(h * 8 + r0 + i) * 132 + c4 * 4] = acc[i];
    __syncthreads();
    #pragma unroll
    for (int rr = 0; rr < 2; ++rr) {
        const int idx = tid + 128 * rr;
        const int row = idx >> 5, q = idx & 31;
        const float4 p0 = *(const float4*)&part[(size_t)row * 132 + q * 4];
        const float4 p1 = *(const float4*)&part[(size_t)(8 + row) * 132 + q * 4];
        const float4 bb = ((const float4*)bo)[q];
        *(float4*)&out[(size_t)(row0 + row) * E + q * 4] =
            make_float4(p0.x + p1.x + bb.x, p0.y + p1.y + bb.y,
                        p0.z + p1.z + bb.z, p0.w + p1.w + bb.w);
    }
}

// ---------------------------------------------------------------------------
extern "C" void kernel_launch(void* const* d_in, const int* in_sizes, int n_in,
                              void* d_out, int out_size, void* d_ws, size_t ws_size,
                              hipStream_t stream) {
    const float* query     = (const float*)d_in[0];
    const float* key       = (const float*)d_in[1];
    const float* value     = (const float*)d_in[2];
    const float* attn_bias = (const float*)d_in[3];
    const float* Wq  = (const float*)d_in[4];
    const float* bq  = (const float*)d_in[5];
    const float* Wk  = (const float*)d_in[6];
    const float* bk  = (const float*)d_in[7];
    const float* Wv  = (const float*)d_in[8];
    const float* bv  = (const float*)d_in[9];
    const float* Wo  = (const float*)d_in[10];
    const float* bo  = (const float*)d_in[11];
    const float* Wfe = (const float*)d_in[12];
    const float* bfe = (const float*)d_in[13];

    float* ws = (float*)d_ws;
    const int NE = N * E;
    float* qw    = ws;
    float* kw    = ws + 1 * NE;
    float* vw    = ws + 2 * NE;
    float* bw    = ws + 3 * NE;
    float* attnw = ws + 4 * NE;

    proj_kernel<<<3 * (N / 16), 256, 0, stream>>>(query, key, value, attn_bias,
                                                  Wq, bq, Wk, bk, Wv, bv,
                                                  Wfe, bfe, qw, kw, vw, bw);
    attn_kernel<<<(N / 8) * H, 64, 0, stream>>>(qw, kw, vw, bw, attnw);
    out_kernel<<<N / 8, 128, 0, stream>>>(attnw, Wo, bo, (float*)d_out);
}